// Round 1
// baseline (2942665.820 us; speedup 1.0000x reference)
//
#include <hip/hip_runtime.h>
#include <stdint.h>

// LSTM: SEQ=4096, HIDDEN=2048, INPUT=128. Persistent cooperative kernel:
// 256 blocks (1/CU) x 512 threads; W_hh register-resident (128 f32/thread).
// R9 = R8 + XCD-hierarchical broadcast:
//  - publish unchanged: 256 blocks, ONE coalesced 32B sc0sc1 store of
//    self-tagged {tag16|f16} slots.
//  - ONLY 8 leader blocks (rank-0 per XCD via HW_REG_XCC_ID + atomicAdd,
//    counters memset per launch) poll the 8KB payload from MALL: per-line
//    requesters drop 256 -> 8, per-round sc-traffic 2MB -> 64KB.
//  - leaders re-broadcast the payload VERBATIM (tags embedded -> no flag,
//    per-word tag check tolerates partial store visibility) into a
//    per-XCD xbuf with sc0 stores (L1-bypass, lands in the XCD's L2).
//  - followers poll xbuf with sc0-only loads: served by the local L2
//    (~200cyc rounds), zero MALL traffic from 248/256 blocks.
//  - cross-replay/stale safety inherited: values are unit-indexed and
//    deterministic, so any stale tag match returns bit-identical data;
//    zero-fill matches only t=1 (want16=0) with h=0 payload == correct.
//  - safety net: follower falls back to the direct MALL poll after 2048
//    failed local rounds (wrong XCC mapping -> slow, not hung).
// ws layout (u32 words): [0,4096) hslots[2][HID]; [4096,4608) fbuf[256] u64;
// [4608,4616) xcnt[8] (memset each launch); [5120,37888) xbuf[8][2][HID].
// Total ws use: 151,552 B.

#define SEQ   4096
#define NIN   128
#define HID   2048
#define NBLK  256
#define NTHR  512
#define NXCD  8

typedef unsigned int u32x4 __attribute__((ext_vector_type(4)));

__device__ __forceinline__ uint64_t ld8_sys(const void* p) {
  uint64_t r;
  asm volatile("global_load_dwordx2 %0, %1, off sc0 sc1\n\t"
               "s_waitcnt vmcnt(0)"
               : "=v"(r) : "v"(p) : "memory");
  return r;
}
__device__ __forceinline__ void st4_sys(void* p, uint32_t v) {
  asm volatile("global_store_dword %0, %1, off sc0 sc1"
               :: "v"(p), "v"(v) : "memory");
}
__device__ __forceinline__ void st8_sys(void* p, uint64_t v) {
  asm volatile("global_store_dwordx2 %0, %1, off sc0 sc1"
               :: "v"(p), "v"(v) : "memory");
}

// f32 -> f16 bits (RNE) in low 16; f16 low bits -> f32
__device__ __forceinline__ uint32_t f32_to_f16lo(float x) {
  uint32_t r;
  asm("v_cvt_f16_f32 %0, %1" : "=v"(r) : "v"(x));
  return r & 0xFFFFu;
}
__device__ __forceinline__ float f16lo_to_f32(uint32_t u) {
  float r;
  asm("v_cvt_f32_f16 %0, %1" : "=v"(r) : "v"(u));
  return r;
}

// DPP full-wave (64-lane) sum; result valid in lane 63.
template <int CTRL>
__device__ __forceinline__ float dpp_add(float x) {
  int y = __builtin_amdgcn_update_dpp(0, __float_as_int(x), CTRL, 0xF, 0xF, true);
  return x + __int_as_float(y);
}
__device__ __forceinline__ float wave_reduce(float x) {
  x = dpp_add<0x111>(x);  // row_shr:1
  x = dpp_add<0x112>(x);  // row_shr:2
  x = dpp_add<0x114>(x);  // row_shr:4
  x = dpp_add<0x118>(x);  // row_shr:8
  x = dpp_add<0x142>(x);  // row_bcast:15
  x = dpp_add<0x143>(x);  // row_bcast:31
  return x;               // lane 63 holds the 64-lane sum
}

__device__ __forceinline__ float fast_sigmoid(float x) {
  return 1.0f / (1.0f + __expf(-x));
}
__device__ __forceinline__ float fast_tanh(float x) {
  return 1.0f - 2.0f / (1.0f + __expf(2.0f * x));
}

// One poll round: 8x global_load_dwordx4 (k-major, contiguous 1KB each),
// per-word tag check. SYS=true -> sc0 sc1 (device/MALL path);
// SYS=false -> sc0 only (L1-bypass, served by the local XCD L2).
template <bool SYS>
__device__ __forceinline__ bool poll8(const char* p0, const char* p1,
                                      u32x4& a0, u32x4& a1, u32x4& a2, u32x4& a3,
                                      u32x4& a4, u32x4& a5, u32x4& a6, u32x4& a7,
                                      uint32_t want16) {
  if constexpr (SYS) {
    asm volatile(
        "global_load_dwordx4 %0, %8, off sc0 sc1\n\t"
        "global_load_dwordx4 %1, %8, off offset:1024 sc0 sc1\n\t"
        "global_load_dwordx4 %2, %8, off offset:2048 sc0 sc1\n\t"
        "global_load_dwordx4 %3, %8, off offset:3072 sc0 sc1\n\t"
        "global_load_dwordx4 %4, %9, off sc0 sc1\n\t"
        "global_load_dwordx4 %5, %9, off offset:1024 sc0 sc1\n\t"
        "global_load_dwordx4 %6, %9, off offset:2048 sc0 sc1\n\t"
        "global_load_dwordx4 %7, %9, off offset:3072 sc0 sc1\n\t"
        "s_waitcnt vmcnt(0)"
        : "=v"(a0), "=v"(a1), "=v"(a2), "=v"(a3),
          "=v"(a4), "=v"(a5), "=v"(a6), "=v"(a7)
        : "v"(p0), "v"(p1) : "memory");
  } else {
    asm volatile(
        "global_load_dwordx4 %0, %8, off sc0\n\t"
        "global_load_dwordx4 %1, %8, off offset:1024 sc0\n\t"
        "global_load_dwordx4 %2, %8, off offset:2048 sc0\n\t"
        "global_load_dwordx4 %3, %8, off offset:3072 sc0\n\t"
        "global_load_dwordx4 %4, %9, off sc0\n\t"
        "global_load_dwordx4 %5, %9, off offset:1024 sc0\n\t"
        "global_load_dwordx4 %6, %9, off offset:2048 sc0\n\t"
        "global_load_dwordx4 %7, %9, off offset:3072 sc0\n\t"
        "s_waitcnt vmcnt(0)"
        : "=v"(a0), "=v"(a1), "=v"(a2), "=v"(a3),
          "=v"(a4), "=v"(a5), "=v"(a6), "=v"(a7)
        : "v"(p0), "v"(p1) : "memory");
  }
  bool ok = true;
#define CK4(A) ok &= ((A[0] >> 16) == want16) & ((A[1] >> 16) == want16) && \
                     ((A[2] >> 16) == want16) & ((A[3] >> 16) == want16);
  CK4(a0) CK4(a1) CK4(a2) CK4(a3) CK4(a4) CK4(a5) CK4(a6) CK4(a7)
#undef CK4
  return __all(ok) != 0;
}

__global__ __launch_bounds__(NTHR, 2) void lstm_persist(
    const float* __restrict__ X, const float* __restrict__ Wih,
    const float* __restrict__ Whh, const float* __restrict__ bih,
    const float* __restrict__ bhh, const float* __restrict__ Wlin,
    const float* __restrict__ blin, float* __restrict__ out,
    uint32_t* __restrict__ ws) {
  const int tid = threadIdx.x;
  const int blk = blockIdx.x;
  const int w   = tid >> 6;   // wave 0..7 -> owns hidden unit blk*8+w
  const int l   = tid & 63;   // lane; covers h-cols [l*32, l*32+32)

  uint32_t* hslots = ws;                         // [2][HID] {tag16|f16 h}
  uint64_t* fbuf   = (uint64_t*)(ws + 2 * HID);  // [NBLK] tagged finals
  uint32_t* xcnt   = ws + 4608;                  // [NXCD] election (memset/launch)
  uint32_t* xbuf   = ws + 5120;                  // [NXCD][2][HID] L2 re-broadcast

  __shared__ __align__(16) float h_lds[2][HID];  // parity double-buffer
  volatile __shared__ uint32_t pub_lds[8];
  __shared__ float red[8];
  __shared__ float fin[NBLK];
  __shared__ uint32_t s_xl;                      // (xcd<<1)|leader

  if (w == 0) __builtin_amdgcn_s_setprio(2);  // critical poll/publish wave

  // ---- init: weights into registers ----
  float whh[4][32];
  float wih[4][2];
  float bias4[4];
#pragma unroll
  for (int G = 0; G < 4; ++G) {
    const size_t Rg = (size_t)(G * HID + blk * 8 + w);
    const float4* src = (const float4*)(Whh + Rg * HID + l * 32);
#pragma unroll
    for (int m = 0; m < 8; ++m) {
      float4 v = src[m];
      whh[G][m * 4 + 0] = v.x; whh[G][m * 4 + 1] = v.y;
      whh[G][m * 4 + 2] = v.z; whh[G][m * 4 + 3] = v.w;
    }
    wih[G][0] = Wih[Rg * NIN + l * 2 + 0];
    wih[G][1] = Wih[Rg * NIN + l * 2 + 1];
    bias4[G]  = bih[Rg] + bhh[Rg];
  }
  const float wlin = Wlin[blk * 8 + w];

  if (tid == 0) {
    // HW_REG_XCC_ID: hwreg id=20, offset 0, size 32 -> imm = (31<<11)|20.
    uint32_t x = __builtin_amdgcn_s_getreg((31 << 11) | 20) & (NXCD - 1);
    const uint32_t r = atomicAdd(&xcnt[x], 1u);   // device-scope
    s_xl = (x << 1) | (r == 0u ? 1u : 0u);
  }
  if (tid < 8) {
    // owner-init payload both parities. Cross-replay staleness safe by
    // exact-tag matching (stale p0 tag16=4096&0xFFFF never equals an even
    // want<=4094; stale p1 tag 4095 only matches want 4095 whose value is
    // deterministic-identical across replays).
    st4_sys(&hslots[0 * HID + blk * 8 + tid], 0u);            // tag0|f16(0)
    st4_sys(&hslots[1 * HID + blk * 8 + tid], 0xFFFF0000u);   // invalid
    pub_lds[tid] = 0xFFFF0000u;
  }
  if (tid == 0)
    st8_sys(&fbuf[blk], 0xFFFFFFFF00000000ull);
  __syncthreads();

  const uint32_t xl = s_xl;
  const bool lead   = (xl & 1u) != 0u;
  uint32_t* xb = xbuf + (size_t)(xl >> 1) * (2 * HID);

  float cc = 0.0f;   // cell state (lane 63)
  float hl = 0.0f;   // last h (lane 63)

  // x prefetch: holds x_{t-1} for the upcoming step t
  float xp0 = X[(size_t)0 * NIN + l * 2 + 0];
  float xp1 = X[(size_t)0 * NIN + l * 2 + 1];

  for (int t = 1; t <= SEQ; ++t) {
    const uint32_t want16 = (uint32_t)(t - 1) & 0xFFFFu;
    const int par = (t - 1) & 1;
    const float x0 = xp0, x1 = xp1;

    // ---- wave 0: acquire the 8KB payload for step t ----
    if (w == 0) {
      u32x4 a0, a1, a2, a3, a4, a5, a6, a7;
      char* xq = (char*)(xb + (size_t)par * HID) + l * 16;
      const char* hp = (const char*)(hslots + (size_t)par * HID) + l * 16;
      if (lead) {
        // leader: low-contention MALL poll (8 requesters/line grid-wide)
        while (!poll8<true>(hp, hp + 4096, a0, a1, a2, a3, a4, a5, a6, a7,
                            want16))
          __builtin_amdgcn_s_sleep(1);
        // re-broadcast VERBATIM into this XCD's L2. No flag needed: tags
        // are embedded per word; followers tolerate partial visibility.
        // No vmcnt wait: a-regs are not rewritten until next step's poll,
        // hundreds of cycles after these stores read them.
        asm volatile(
            "global_store_dwordx4 %8, %0, off sc0\n\t"
            "global_store_dwordx4 %8, %1, off offset:1024 sc0\n\t"
            "global_store_dwordx4 %8, %2, off offset:2048 sc0\n\t"
            "global_store_dwordx4 %8, %3, off offset:3072 sc0\n\t"
            "global_store_dwordx4 %9, %4, off sc0\n\t"
            "global_store_dwordx4 %9, %5, off offset:1024 sc0\n\t"
            "global_store_dwordx4 %9, %6, off offset:2048 sc0\n\t"
            "global_store_dwordx4 %9, %7, off offset:3072 sc0\n\t"
            :: "v"(a0), "v"(a1), "v"(a2), "v"(a3),
               "v"(a4), "v"(a5), "v"(a6), "v"(a7),
               "v"(xq), "v"(xq + 4096)
            : "memory");
      } else {
        // follower: cheap local-L2 rounds; MALL fallback = deadlock-proof.
        int spins = 0;
        for (;;) {
          if (poll8<false>(xq, xq + 4096, a0, a1, a2, a3, a4, a5, a6, a7,
                           want16))
            break;
          if (++spins > 2048) {
            while (!poll8<true>(hp, hp + 4096, a0, a1, a2, a3, a4, a5, a6,
                                a7, want16))
              __builtin_amdgcn_s_sleep(1);
            break;
          }
          __builtin_amdgcn_s_sleep(1);
        }
      }
      // fan out: cvt f16->f32, swizzled ds_write_b128.
      // load k, lane l holds units [256k + 4l, 256k + 4l + 4) -> uu = 64k+l,
      // write pos ph = 64k + (l ^ (l>>3)).
      const int lsw = l ^ (l >> 3);
#define FAN(A, K)                                                   \
      {                                                             \
        float4 hw;                                                  \
        hw.x = f16lo_to_f32(A[0] & 0xFFFFu);                        \
        hw.y = f16lo_to_f32(A[1] & 0xFFFFu);                        \
        hw.z = f16lo_to_f32(A[2] & 0xFFFFu);                        \
        hw.w = f16lo_to_f32(A[3] & 0xFFFFu);                        \
        *(float4*)&h_lds[par][(64 * K + lsw) * 4] = hw;             \
      }
      FAN(a0, 0) FAN(a1, 1) FAN(a2, 2) FAN(a3, 3)
      FAN(a4, 4) FAN(a5, 5) FAN(a6, 6) FAN(a7, 7)
#undef FAN
    }
    __syncthreads();  // (D) — h staged; the only full barrier per step

    // prefetch x for next step; hides under FMA phase
    {
      const int tn = (t < SEQ) ? t : SEQ - 1;
      xp0 = X[(size_t)tn * NIN + l * 2 + 0];
      xp1 = X[(size_t)tn * NIN + l * 2 + 1];
    }

    const float* hb = h_lds[par];
    float acc0 = 0.f, acc1 = 0.f, acc2 = 0.f, acc3 = 0.f;
#pragma unroll
    for (int i = 0; i < 8; ++i) {
      const int uu = l * 8 + i;
      const int ph = uu ^ ((uu >> 3) & 7);
      const float4 hv = *(const float4*)&hb[ph * 4];
      acc0 = fmaf(whh[0][i * 4 + 0], hv.x, acc0);
      acc0 = fmaf(whh[0][i * 4 + 1], hv.y, acc0);
      acc0 = fmaf(whh[0][i * 4 + 2], hv.z, acc0);
      acc0 = fmaf(whh[0][i * 4 + 3], hv.w, acc0);
      acc1 = fmaf(whh[1][i * 4 + 0], hv.x, acc1);
      acc1 = fmaf(whh[1][i * 4 + 1], hv.y, acc1);
      acc1 = fmaf(whh[1][i * 4 + 2], hv.z, acc1);
      acc1 = fmaf(whh[1][i * 4 + 3], hv.w, acc1);
      acc2 = fmaf(whh[2][i * 4 + 0], hv.x, acc2);
      acc2 = fmaf(whh[2][i * 4 + 1], hv.y, acc2);
      acc2 = fmaf(whh[2][i * 4 + 2], hv.z, acc2);
      acc2 = fmaf(whh[2][i * 4 + 3], hv.w, acc2);
      acc3 = fmaf(whh[3][i * 4 + 0], hv.x, acc3);
      acc3 = fmaf(whh[3][i * 4 + 1], hv.y, acc3);
      acc3 = fmaf(whh[3][i * 4 + 2], hv.z, acc3);
      acc3 = fmaf(whh[3][i * 4 + 3], hv.w, acc3);
    }
    acc0 = fmaf(wih[0][0], x0, acc0); acc0 = fmaf(wih[0][1], x1, acc0);
    acc1 = fmaf(wih[1][0], x0, acc1); acc1 = fmaf(wih[1][1], x1, acc1);
    acc2 = fmaf(wih[2][0], x0, acc2); acc2 = fmaf(wih[2][1], x1, acc2);
    acc3 = fmaf(wih[3][0], x0, acc3); acc3 = fmaf(wih[3][1], x1, acc3);

    acc0 = wave_reduce(acc0);
    acc1 = wave_reduce(acc1);
    acc2 = wave_reduce(acc2);
    acc3 = wave_reduce(acc3);

    if (l == 63) {  // own unit: activations + cell update, post to LDS
      const float i_ = fast_sigmoid(acc0 + bias4[0]);
      const float f_ = fast_sigmoid(acc1 + bias4[1]);
      const float g_ = fast_tanh(acc2 + bias4[2]);
      const float o_ = fast_sigmoid(acc3 + bias4[3]);
      cc = fmaf(f_, cc, i_ * g_);
      const float h = o_ * fast_tanh(cc);
      hl = h;
      pub_lds[w] = ((uint32_t)t << 16) | f32_to_f16lo(h);
    }
    // wave 0: gather 8 posted words (LDS spin), ONE coalesced 32B store.
    if (w == 0 && l < 8) {
      uint32_t v;
      do { v = pub_lds[l]; } while ((v >> 16) != (uint32_t)t);
      st4_sys(&hslots[(size_t)(t & 1) * HID + blk * 8 + l], v);
    }
  }

  // ---- final head: out = h_last . W_lin + b_lin ----
  if (l == 63) red[w] = hl * wlin;
  __syncthreads();
  if (tid == 0) {
    float s = red[0] + red[1] + red[2] + red[3] +
              red[4] + red[5] + red[6] + red[7];
    uint64_t pv = (uint64_t)__float_as_uint(s) |
                  ((uint64_t)(uint32_t)(SEQ + 1) << 32);
    st8_sys(&fbuf[blk], pv);
  }
  if (blk == 0) {
    if (tid < NBLK) {
      uint64_t v;
      do {
        v = ld8_sys(&fbuf[tid]);
      } while ((uint32_t)(v >> 32) != (uint32_t)(SEQ + 1));
      fin[tid] = __uint_as_float((uint32_t)v);
    }
    __syncthreads();
    if (tid == 0) {
      float s = blin[0];
      for (int i = 0; i < NBLK; ++i) s += fin[i];
      out[0] = s;  // deterministic: fixed summation order, no atomics
    }
  }
}

extern "C" void kernel_launch(void* const* d_in, const int* in_sizes, int n_in,
                              void* d_out, int out_size, void* d_ws,
                              size_t ws_size, hipStream_t stream) {
  const float* X    = (const float*)d_in[0];
  const float* Wih  = (const float*)d_in[1];
  const float* Whh  = (const float*)d_in[2];
  const float* bih  = (const float*)d_in[3];
  const float* bhh  = (const float*)d_in[4];
  const float* Wlin = (const float*)d_in[5];
  const float* blin = (const float*)d_in[6];
  float* out   = (float*)d_out;
  uint32_t* ws = (uint32_t*)d_ws;  // uses 151,552 B (hslots+fbuf+xcnt+xbuf)

  // zero the 8 per-XCD leader-election counters (u32 @ byte 18432).
  // Graph-capture-safe stream op; replays re-run it before the kernel.
  hipMemsetAsync((void*)((char*)d_ws + 18432), 0, NXCD * sizeof(uint32_t),
                 stream);

  void* args[] = {(void*)&X,    (void*)&Wih,  (void*)&Whh,
                  (void*)&bih,  (void*)&bhh,  (void*)&Wlin,
                  (void*)&blin, (void*)&out,  (void*)&ws};
  hipLaunchCooperativeKernel((const void*)lstm_persist, dim3(NBLK), dim3(NTHR),
                             args, 0, stream);
}

// Round 2
// 14039.766 us; speedup vs baseline: 209.5951x; 209.5951x over previous
//
#include <hip/hip_runtime.h>
#include <stdint.h>

// LSTM: SEQ=4096, HIDDEN=2048, INPUT=128. Persistent cooperative kernel.
// R10 = R8 structure (proven 2.28us/step) with rendezvous agents halved:
//  - 128 blocks x 1024 threads (16 waves). Wave w owns unit blk*16+w.
//  - W_hh register-resident as packed f16x2 (64 u32/thread) consumed by
//    v_dot2_f32_f16; h is already published as f16, so the fanout packs
//    tag-stripped f16 PAIRS straight into LDS (no f32 cvt).
//  - publish: 128 blocks x ONE coalesced 64B sc0sc1 store of self-tagged
//    {tag16|f16} slots (16 units/block).
//  - poll: ONLY wave 0 of each block; 8x global_load_dwordx4 in ONE asm
//    stmt, k-major contiguous 1KB per instr. Per-line MALL requesters
//    drop 256 -> 128 (the proven R7->R8 direction, continued).
// R9's XCD-L2 multicast is abandoned: leader/follower on different
// physical XCDs pins a stale line in the consumer L2 (no cross-XCD
// invalidation) -> 2048-spin fallback every step (measured 2.9s).
// Cross-replay staleness safe by exact-tag matching (stale p0 tag16=4096
// never equals an even want<=4094; stale p1 tag 4095 only matches want
// 4095 whose value is deterministic-identical across replays).
// ws layout (u32): [0,4096) hslots[2][HID]; [4096,4352) fbuf[128] u64.

#define SEQ   4096
#define NIN   128
#define HID   2048
#define NBLK  128
#define NTHR  1024
#define UPB   16      // units per block = waves per block

typedef unsigned int u32x4 __attribute__((ext_vector_type(4)));
typedef _Float16 half2_t __attribute__((ext_vector_type(2)));

__device__ __forceinline__ uint64_t ld8_sys(const void* p) {
  uint64_t r;
  asm volatile("global_load_dwordx2 %0, %1, off sc0 sc1\n\t"
               "s_waitcnt vmcnt(0)"
               : "=v"(r) : "v"(p) : "memory");
  return r;
}
__device__ __forceinline__ void st4_sys(void* p, uint32_t v) {
  asm volatile("global_store_dword %0, %1, off sc0 sc1"
               :: "v"(p), "v"(v) : "memory");
}
__device__ __forceinline__ void st8_sys(void* p, uint64_t v) {
  asm volatile("global_store_dwordx2 %0, %1, off sc0 sc1"
               :: "v"(p), "v"(v) : "memory");
}

// f32 -> f16 bits (RNE) in low 16; f16 low bits -> f32
__device__ __forceinline__ uint32_t f32_to_f16lo(float x) {
  uint32_t r;
  asm("v_cvt_f16_f32 %0, %1" : "=v"(r) : "v"(x));
  return r & 0xFFFFu;
}
__device__ __forceinline__ float f16lo_to_f32(uint32_t u) {
  float r;
  asm("v_cvt_f32_f16 %0, %1" : "=v"(r) : "v"(u));
  return r;
}
__device__ __forceinline__ uint32_t pack_f16x2(float a, float b) {
  return f32_to_f16lo(a) | (f32_to_f16lo(b) << 16);
}
__device__ __forceinline__ half2_t as_h2(uint32_t u) {
  union { uint32_t u; half2_t h; } x; x.u = u; return x.h;
}

// packed f16 dot2 with f32 accumulate
#if defined(__has_builtin)
#if __has_builtin(__builtin_amdgcn_fdot2)
#define HAVE_FDOT2 1
#endif
#endif
__device__ __forceinline__ float dot2(uint32_t w, uint32_t h, float acc) {
#ifdef HAVE_FDOT2
  return __builtin_amdgcn_fdot2(as_h2(w), as_h2(h), acc, false);
#else
  acc = fmaf(f16lo_to_f32(w & 0xFFFFu), f16lo_to_f32(h & 0xFFFFu), acc);
  acc = fmaf(f16lo_to_f32(w >> 16),     f16lo_to_f32(h >> 16),     acc);
  return acc;
#endif
}

// DPP full-wave (64-lane) sum; result valid in lane 63.
template <int CTRL>
__device__ __forceinline__ float dpp_add(float x) {
  int y = __builtin_amdgcn_update_dpp(0, __float_as_int(x), CTRL, 0xF, 0xF, true);
  return x + __int_as_float(y);
}
__device__ __forceinline__ float wave_reduce(float x) {
  x = dpp_add<0x111>(x);  // row_shr:1
  x = dpp_add<0x112>(x);  // row_shr:2
  x = dpp_add<0x114>(x);  // row_shr:4
  x = dpp_add<0x118>(x);  // row_shr:8
  x = dpp_add<0x142>(x);  // row_bcast:15
  x = dpp_add<0x143>(x);  // row_bcast:31
  return x;               // lane 63 holds the 64-lane sum
}

__device__ __forceinline__ float fast_sigmoid(float x) {
  return 1.0f / (1.0f + __expf(-x));
}
__device__ __forceinline__ float fast_tanh(float x) {
  return 1.0f - 2.0f / (1.0f + __expf(2.0f * x));
}

// quad-position swizzle (16B granularity), involution: q ^ ((q>>3)&7)
__device__ __forceinline__ int qpos(int q) { return q ^ ((q >> 3) & 7); }

// One poll round: 8x global_load_dwordx4 (k-major, contiguous 1KB each),
// per-word tag check. sc0 sc1 = device/MALL path.
__device__ __forceinline__ bool poll8(const char* p0, const char* p1,
                                      u32x4& a0, u32x4& a1, u32x4& a2, u32x4& a3,
                                      u32x4& a4, u32x4& a5, u32x4& a6, u32x4& a7,
                                      uint32_t want16) {
  asm volatile(
      "global_load_dwordx4 %0, %8, off sc0 sc1\n\t"
      "global_load_dwordx4 %1, %8, off offset:1024 sc0 sc1\n\t"
      "global_load_dwordx4 %2, %8, off offset:2048 sc0 sc1\n\t"
      "global_load_dwordx4 %3, %8, off offset:3072 sc0 sc1\n\t"
      "global_load_dwordx4 %4, %9, off sc0 sc1\n\t"
      "global_load_dwordx4 %5, %9, off offset:1024 sc0 sc1\n\t"
      "global_load_dwordx4 %6, %9, off offset:2048 sc0 sc1\n\t"
      "global_load_dwordx4 %7, %9, off offset:3072 sc0 sc1\n\t"
      "s_waitcnt vmcnt(0)"
      : "=v"(a0), "=v"(a1), "=v"(a2), "=v"(a3),
        "=v"(a4), "=v"(a5), "=v"(a6), "=v"(a7)
      : "v"(p0), "v"(p1) : "memory");
  bool ok = true;
#define CK4(A) ok &= ((A[0] >> 16) == want16) & ((A[1] >> 16) == want16) && \
                     ((A[2] >> 16) == want16) & ((A[3] >> 16) == want16);
  CK4(a0) CK4(a1) CK4(a2) CK4(a3) CK4(a4) CK4(a5) CK4(a6) CK4(a7)
#undef CK4
  return __all(ok) != 0;
}

__global__ __launch_bounds__(NTHR, 4) void lstm_persist(
    const float* __restrict__ X, const float* __restrict__ Wih,
    const float* __restrict__ Whh, const float* __restrict__ bih,
    const float* __restrict__ bhh, const float* __restrict__ Wlin,
    const float* __restrict__ blin, float* __restrict__ out,
    uint32_t* __restrict__ ws) {
  const int tid = threadIdx.x;
  const int blk = blockIdx.x;
  const int w   = tid >> 6;   // wave 0..15 -> owns hidden unit blk*16+w
  const int l   = tid & 63;   // lane; covers h-cols [l*32, l*32+32)

  uint32_t* hslots = ws;                         // [2][HID] {tag16|f16 h}
  uint64_t* fbuf   = (uint64_t*)(ws + 2 * HID);  // [NBLK] tagged finals

  // h staged as packed f16 PAIRS: 1024 u32 per parity, quad-swizzled.
  __shared__ __align__(16) uint32_t hp_lds[2][1024];
  volatile __shared__ uint32_t pub_lds[UPB];
  __shared__ float red[UPB];
  __shared__ float fin[NBLK];

  if (w == 0) __builtin_amdgcn_s_setprio(2);  // critical poll/publish wave

  // ---- init: weights into registers, packed f16x2 ----
  uint32_t whh[4][16];
  float wih[4][2];
  float bias4[4];
#pragma unroll
  for (int G = 0; G < 4; ++G) {
    const size_t Rg = (size_t)(G * HID + blk * UPB + w);
    const float4* src = (const float4*)(Whh + Rg * HID + l * 32);
#pragma unroll
    for (int m = 0; m < 8; ++m) {
      float4 v = src[m];
      whh[G][m * 2 + 0] = pack_f16x2(v.x, v.y);
      whh[G][m * 2 + 1] = pack_f16x2(v.z, v.w);
    }
    wih[G][0] = Wih[Rg * NIN + l * 2 + 0];
    wih[G][1] = Wih[Rg * NIN + l * 2 + 1];
    bias4[G]  = bih[Rg] + bhh[Rg];
  }
  const float wlin = Wlin[blk * UPB + w];

  if (tid < UPB) {
    // owner-init payload both parities (exact-tag matching makes stale
    // cross-replay data safe; see header).
    st4_sys(&hslots[0 * HID + blk * UPB + tid], 0u);           // tag0|f16(0)
    st4_sys(&hslots[1 * HID + blk * UPB + tid], 0xFFFF0000u);  // invalid
    pub_lds[tid] = 0xFFFF0000u;
  }
  if (tid == 0)
    st8_sys(&fbuf[blk], 0xFFFFFFFF00000000ull);
  __syncthreads();

  float cc = 0.0f;   // cell state (lane 63)
  float hl = 0.0f;   // last h (lane 63)

  // x prefetch: holds x_{t-1} for the upcoming step t
  float xp0 = X[(size_t)0 * NIN + l * 2 + 0];
  float xp1 = X[(size_t)0 * NIN + l * 2 + 1];

  for (int t = 1; t <= SEQ; ++t) {
    const uint32_t want16 = (uint32_t)(t - 1) & 0xFFFFu;
    const int par = (t - 1) & 1;
    const float x0 = xp0, x1 = xp1;

    // ---- wave 0: poll whole 8KB payload, fully line-coalesced ----
    if (w == 0) {
      const char* hp = (const char*)(hslots + (size_t)par * HID) + l * 16;
      u32x4 a0, a1, a2, a3, a4, a5, a6, a7;
      while (!poll8(hp, hp + 4096, a0, a1, a2, a3, a4, a5, a6, a7, want16))
        __builtin_amdgcn_s_sleep(1);
      // fan out tag-stripped f16 pairs. Load k, lane l holds units
      // u0=256k+4l..+3 -> pairs j0=128k+2l,+1 -> quad q=32k+(l>>1),
      // half (l&1). Swizzled by qpos(q) to kill compute-read conflicts.
      const int qbase = l >> 1;
      const int woff  = (l & 1) * 2;
#define FAN(A, K)                                                     \
      {                                                               \
        uint32_t pp0 = (A[0] & 0xFFFFu) | (A[1] << 16);               \
        uint32_t pp1 = (A[2] & 0xFFFFu) | (A[3] << 16);               \
        const int q = 32 * K + qbase;                                 \
        uint2 pv; pv.x = pp0; pv.y = pp1;                             \
        *(uint2*)&hp_lds[par][qpos(q) * 4 + woff] = pv;               \
      }
      FAN(a0, 0) FAN(a1, 1) FAN(a2, 2) FAN(a3, 3)
      FAN(a4, 4) FAN(a5, 5) FAN(a6, 6) FAN(a7, 7)
#undef FAN
    }
    __syncthreads();  // h staged; the only full barrier per step

    // prefetch x for next step; hides under dot2 phase
    {
      const int tn = (t < SEQ) ? t : SEQ - 1;
      xp0 = X[(size_t)tn * NIN + l * 2 + 0];
      xp1 = X[(size_t)tn * NIN + l * 2 + 1];
    }

    const uint32_t* hq = hp_lds[par];
    float acc0 = 0.f, acc1 = 0.f, acc2 = 0.f, acc3 = 0.f;
#pragma unroll
    for (int i4 = 0; i4 < 4; ++i4) {
      const int q = (l << 2) | i4;                   // quad of pairs
      const u32x4 hv = *(const u32x4*)&hq[qpos(q) * 4];
#pragma unroll
      for (int jj = 0; jj < 4; ++jj) {
        const int p = i4 * 4 + jj;                   // weight pair index
        acc0 = dot2(whh[0][p], hv[jj], acc0);
        acc1 = dot2(whh[1][p], hv[jj], acc1);
        acc2 = dot2(whh[2][p], hv[jj], acc2);
        acc3 = dot2(whh[3][p], hv[jj], acc3);
      }
    }
    acc0 = fmaf(wih[0][0], x0, acc0); acc0 = fmaf(wih[0][1], x1, acc0);
    acc1 = fmaf(wih[1][0], x0, acc1); acc1 = fmaf(wih[1][1], x1, acc1);
    acc2 = fmaf(wih[2][0], x0, acc2); acc2 = fmaf(wih[2][1], x1, acc2);
    acc3 = fmaf(wih[3][0], x0, acc3); acc3 = fmaf(wih[3][1], x1, acc3);

    acc0 = wave_reduce(acc0);
    acc1 = wave_reduce(acc1);
    acc2 = wave_reduce(acc2);
    acc3 = wave_reduce(acc3);

    if (l == 63) {  // own unit: activations + cell update, post to LDS
      const float i_ = fast_sigmoid(acc0 + bias4[0]);
      const float f_ = fast_sigmoid(acc1 + bias4[1]);
      const float g_ = fast_tanh(acc2 + bias4[2]);
      const float o_ = fast_sigmoid(acc3 + bias4[3]);
      cc = fmaf(f_, cc, i_ * g_);
      const float h = o_ * fast_tanh(cc);
      hl = h;
      pub_lds[w] = ((uint32_t)t << 16) | f32_to_f16lo(h);
    }
    // wave 0: gather 16 posted words (LDS spin), ONE coalesced 64B store.
    if (w == 0 && l < UPB) {
      uint32_t v;
      do { v = pub_lds[l]; } while ((v >> 16) != (uint32_t)t);
      st4_sys(&hslots[(size_t)(t & 1) * HID + blk * UPB + l], v);
    }
  }

  // ---- final head: out = h_last . W_lin + b_lin ----
  if (l == 63) red[w] = hl * wlin;
  __syncthreads();
  if (tid == 0) {
    float s = 0.0f;
#pragma unroll
    for (int i = 0; i < UPB; ++i) s += red[i];
    uint64_t pv = (uint64_t)__float_as_uint(s) |
                  ((uint64_t)(uint32_t)(SEQ + 1) << 32);
    st8_sys(&fbuf[blk], pv);
  }
  if (blk == 0) {
    if (tid < NBLK) {
      uint64_t v;
      do {
        v = ld8_sys(&fbuf[tid]);
      } while ((uint32_t)(v >> 32) != (uint32_t)(SEQ + 1));
      fin[tid] = __uint_as_float((uint32_t)v);
    }
    __syncthreads();
    if (tid == 0) {
      float s = blin[0];
      for (int i = 0; i < NBLK; ++i) s += fin[i];
      out[0] = s;  // deterministic: fixed summation order, no atomics
    }
  }
}

extern "C" void kernel_launch(void* const* d_in, const int* in_sizes, int n_in,
                              void* d_out, int out_size, void* d_ws,
                              size_t ws_size, hipStream_t stream) {
  const float* X    = (const float*)d_in[0];
  const float* Wih  = (const float*)d_in[1];
  const float* Whh  = (const float*)d_in[2];
  const float* bih  = (const float*)d_in[3];
  const float* bhh  = (const float*)d_in[4];
  const float* Wlin = (const float*)d_in[5];
  const float* blin = (const float*)d_in[6];
  float* out   = (float*)d_out;
  uint32_t* ws = (uint32_t*)d_ws;  // uses 17,408 B (hslots + fbuf)

  void* args[] = {(void*)&X,    (void*)&Wih,  (void*)&Whh,
                  (void*)&bih,  (void*)&bhh,  (void*)&Wlin,
                  (void*)&blin, (void*)&out,  (void*)&ws};
  hipLaunchCooperativeKernel((const void*)lstm_persist, dim3(NBLK), dim3(NTHR),
                             args, 0, stream);
}

// Round 3
// 9850.786 us; speedup vs baseline: 298.7240x; 1.4252x over previous
//
#include <hip/hip_runtime.h>
#include <stdint.h>

// LSTM: SEQ=4096, HIDDEN=2048, INPUT=128. Persistent cooperative kernel.
// R11 = R8 topology (proven 2.28us/step: 256 blocks x 512 thr, 8 waves,
// 1 block/CU) + R10's verified f16 arithmetic (absmax 0.0):
//  - W_hh register-resident as packed f16x2 (64 u32/thread) consumed by
//    v_dot2_f32_f16; h is already published as f16, so wave 0's fanout
//    packs tag-stripped f16 PAIRS straight into LDS (no f32 cvt, 8B
//    stores) and the h staging buffer halves to 8KB.
//  - rendezvous path byte-identical to R8: self-tagged {tag16|f16} slots,
//    ONE coalesced 32B sc0sc1 publish store per block, single-wave
//    k-major coalesced poll (8x dwordx4 in one asm stmt).
// R9 (XCD-L2 multicast) abandoned: cross-XCD stale-line pinning (2.9s).
// R10 (128x1024) abandoned: halving blocks doubles per-CU compute and
// showed the rendezvous is latency-bound, not requester-queueing-bound.
// Cross-replay staleness safe by exact-tag matching (stale p0 tag16=4096
// never equals an even want<=4094; stale p1 tag 4095 only matches want
// 4095 whose value is deterministic-identical across replays).
// ws layout (u32): [0,4096) hslots[2][HID]; [4096,4608) fbuf[256] u64.

#define SEQ   4096
#define NIN   128
#define HID   2048
#define NBLK  256
#define NTHR  512
#define UPB   8       // units per block = waves per block

typedef unsigned int u32x4 __attribute__((ext_vector_type(4)));
typedef _Float16 half2_t __attribute__((ext_vector_type(2)));

__device__ __forceinline__ uint64_t ld8_sys(const void* p) {
  uint64_t r;
  asm volatile("global_load_dwordx2 %0, %1, off sc0 sc1\n\t"
               "s_waitcnt vmcnt(0)"
               : "=v"(r) : "v"(p) : "memory");
  return r;
}
__device__ __forceinline__ void st4_sys(void* p, uint32_t v) {
  asm volatile("global_store_dword %0, %1, off sc0 sc1"
               :: "v"(p), "v"(v) : "memory");
}
__device__ __forceinline__ void st8_sys(void* p, uint64_t v) {
  asm volatile("global_store_dwordx2 %0, %1, off sc0 sc1"
               :: "v"(p), "v"(v) : "memory");
}

// f32 -> f16 bits (RNE) in low 16; f16 low bits -> f32
__device__ __forceinline__ uint32_t f32_to_f16lo(float x) {
  uint32_t r;
  asm("v_cvt_f16_f32 %0, %1" : "=v"(r) : "v"(x));
  return r & 0xFFFFu;
}
__device__ __forceinline__ float f16lo_to_f32(uint32_t u) {
  float r;
  asm("v_cvt_f32_f16 %0, %1" : "=v"(r) : "v"(u));
  return r;
}
__device__ __forceinline__ uint32_t pack_f16x2(float a, float b) {
  return f32_to_f16lo(a) | (f32_to_f16lo(b) << 16);
}
__device__ __forceinline__ half2_t as_h2(uint32_t u) {
  union { uint32_t u; half2_t h; } x; x.u = u; return x.h;
}

// packed f16 dot2 with f32 accumulate (verified bit-correct in R10)
#if defined(__has_builtin)
#if __has_builtin(__builtin_amdgcn_fdot2)
#define HAVE_FDOT2 1
#endif
#endif
__device__ __forceinline__ float dot2(uint32_t w, uint32_t h, float acc) {
#ifdef HAVE_FDOT2
  return __builtin_amdgcn_fdot2(as_h2(w), as_h2(h), acc, false);
#else
  acc = fmaf(f16lo_to_f32(w & 0xFFFFu), f16lo_to_f32(h & 0xFFFFu), acc);
  acc = fmaf(f16lo_to_f32(w >> 16),     f16lo_to_f32(h >> 16),     acc);
  return acc;
#endif
}

// DPP full-wave (64-lane) sum; result valid in lane 63.
template <int CTRL>
__device__ __forceinline__ float dpp_add(float x) {
  int y = __builtin_amdgcn_update_dpp(0, __float_as_int(x), CTRL, 0xF, 0xF, true);
  return x + __int_as_float(y);
}
__device__ __forceinline__ float wave_reduce(float x) {
  x = dpp_add<0x111>(x);  // row_shr:1
  x = dpp_add<0x112>(x);  // row_shr:2
  x = dpp_add<0x114>(x);  // row_shr:4
  x = dpp_add<0x118>(x);  // row_shr:8
  x = dpp_add<0x142>(x);  // row_bcast:15
  x = dpp_add<0x143>(x);  // row_bcast:31
  return x;               // lane 63 holds the 64-lane sum
}

__device__ __forceinline__ float fast_sigmoid(float x) {
  return 1.0f / (1.0f + __expf(-x));
}
__device__ __forceinline__ float fast_tanh(float x) {
  return 1.0f - 2.0f / (1.0f + __expf(2.0f * x));
}

// quad-position swizzle (16B granularity), involution: q ^ ((q>>3)&7)
__device__ __forceinline__ int qpos(int q) { return q ^ ((q >> 3) & 7); }

// One poll round: 8x global_load_dwordx4 (k-major, contiguous 1KB each),
// per-word tag check. sc0 sc1 = device/MALL path.
__device__ __forceinline__ bool poll8(const char* p0, const char* p1,
                                      u32x4& a0, u32x4& a1, u32x4& a2, u32x4& a3,
                                      u32x4& a4, u32x4& a5, u32x4& a6, u32x4& a7,
                                      uint32_t want16) {
  asm volatile(
      "global_load_dwordx4 %0, %8, off sc0 sc1\n\t"
      "global_load_dwordx4 %1, %8, off offset:1024 sc0 sc1\n\t"
      "global_load_dwordx4 %2, %8, off offset:2048 sc0 sc1\n\t"
      "global_load_dwordx4 %3, %8, off offset:3072 sc0 sc1\n\t"
      "global_load_dwordx4 %4, %9, off sc0 sc1\n\t"
      "global_load_dwordx4 %5, %9, off offset:1024 sc0 sc1\n\t"
      "global_load_dwordx4 %6, %9, off offset:2048 sc0 sc1\n\t"
      "global_load_dwordx4 %7, %9, off offset:3072 sc0 sc1\n\t"
      "s_waitcnt vmcnt(0)"
      : "=v"(a0), "=v"(a1), "=v"(a2), "=v"(a3),
        "=v"(a4), "=v"(a5), "=v"(a6), "=v"(a7)
      : "v"(p0), "v"(p1) : "memory");
  bool ok = true;
#define CK4(A) ok &= ((A[0] >> 16) == want16) & ((A[1] >> 16) == want16) && \
                     ((A[2] >> 16) == want16) & ((A[3] >> 16) == want16);
  CK4(a0) CK4(a1) CK4(a2) CK4(a3) CK4(a4) CK4(a5) CK4(a6) CK4(a7)
#undef CK4
  return __all(ok) != 0;
}

__global__ __launch_bounds__(NTHR, 2) void lstm_persist(
    const float* __restrict__ X, const float* __restrict__ Wih,
    const float* __restrict__ Whh, const float* __restrict__ bih,
    const float* __restrict__ bhh, const float* __restrict__ Wlin,
    const float* __restrict__ blin, float* __restrict__ out,
    uint32_t* __restrict__ ws) {
  const int tid = threadIdx.x;
  const int blk = blockIdx.x;
  const int w   = tid >> 6;   // wave 0..7 -> owns hidden unit blk*8+w
  const int l   = tid & 63;   // lane; covers h-cols [l*32, l*32+32)

  uint32_t* hslots = ws;                         // [2][HID] {tag16|f16 h}
  uint64_t* fbuf   = (uint64_t*)(ws + 2 * HID);  // [NBLK] tagged finals

  // h staged as packed f16 PAIRS: 1024 u32 per parity, quad-swizzled.
  __shared__ __align__(16) uint32_t hp_lds[2][1024];
  volatile __shared__ uint32_t pub_lds[UPB];
  __shared__ float red[UPB];
  __shared__ float fin[NBLK];

  if (w == 0) __builtin_amdgcn_s_setprio(2);  // critical poll/publish wave

  // ---- init: weights into registers, packed f16x2 ----
  uint32_t whh[4][16];
  float wih[4][2];
  float bias4[4];
#pragma unroll
  for (int G = 0; G < 4; ++G) {
    const size_t Rg = (size_t)(G * HID + blk * UPB + w);
    const float4* src = (const float4*)(Whh + Rg * HID + l * 32);
#pragma unroll
    for (int m = 0; m < 8; ++m) {
      float4 v = src[m];
      whh[G][m * 2 + 0] = pack_f16x2(v.x, v.y);
      whh[G][m * 2 + 1] = pack_f16x2(v.z, v.w);
    }
    wih[G][0] = Wih[Rg * NIN + l * 2 + 0];
    wih[G][1] = Wih[Rg * NIN + l * 2 + 1];
    bias4[G]  = bih[Rg] + bhh[Rg];
  }
  const float wlin = Wlin[blk * UPB + w];

  if (tid < UPB) {
    // owner-init payload both parities (exact-tag matching makes stale
    // cross-replay data safe; see header).
    st4_sys(&hslots[0 * HID + blk * UPB + tid], 0u);           // tag0|f16(0)
    st4_sys(&hslots[1 * HID + blk * UPB + tid], 0xFFFF0000u);  // invalid
    pub_lds[tid] = 0xFFFF0000u;
  }
  if (tid == 0)
    st8_sys(&fbuf[blk], 0xFFFFFFFF00000000ull);
  __syncthreads();

  float cc = 0.0f;   // cell state (lane 63)
  float hl = 0.0f;   // last h (lane 63)

  // x prefetch: holds x_{t-1} for the upcoming step t
  float xp0 = X[(size_t)0 * NIN + l * 2 + 0];
  float xp1 = X[(size_t)0 * NIN + l * 2 + 1];

  for (int t = 1; t <= SEQ; ++t) {
    const uint32_t want16 = (uint32_t)(t - 1) & 0xFFFFu;
    const int par = (t - 1) & 1;
    const float x0 = xp0, x1 = xp1;

    // ---- wave 0: poll whole 8KB payload, fully line-coalesced ----
    if (w == 0) {
      const char* hp = (const char*)(hslots + (size_t)par * HID) + l * 16;
      u32x4 a0, a1, a2, a3, a4, a5, a6, a7;
      while (!poll8(hp, hp + 4096, a0, a1, a2, a3, a4, a5, a6, a7, want16))
        __builtin_amdgcn_s_sleep(1);
      // fan out tag-stripped f16 pairs. Load k, lane l holds units
      // u0=256k+4l..+3 -> pairs j0=128k+2l,+1 -> quad q=32k+(l>>1),
      // half (l&1). Swizzled by qpos(q) to spread compute-read banks.
      const int qbase = l >> 1;
      const int woff  = (l & 1) * 2;
#define FAN(A, K)                                                     \
      {                                                               \
        uint32_t pp0 = (A[0] & 0xFFFFu) | (A[1] << 16);               \
        uint32_t pp1 = (A[2] & 0xFFFFu) | (A[3] << 16);               \
        const int q = 32 * K + qbase;                                 \
        uint2 pv; pv.x = pp0; pv.y = pp1;                             \
        *(uint2*)&hp_lds[par][qpos(q) * 4 + woff] = pv;               \
      }
      FAN(a0, 0) FAN(a1, 1) FAN(a2, 2) FAN(a3, 3)
      FAN(a4, 4) FAN(a5, 5) FAN(a6, 6) FAN(a7, 7)
#undef FAN
    }
    __syncthreads();  // h staged; the only full barrier per step

    // prefetch x for next step; hides under dot2 phase
    {
      const int tn = (t < SEQ) ? t : SEQ - 1;
      xp0 = X[(size_t)tn * NIN + l * 2 + 0];
      xp1 = X[(size_t)tn * NIN + l * 2 + 1];
    }

    const uint32_t* hq = hp_lds[par];
    float acc0 = 0.f, acc1 = 0.f, acc2 = 0.f, acc3 = 0.f;
#pragma unroll
    for (int i4 = 0; i4 < 4; ++i4) {
      const int q = (l << 2) | i4;                   // quad of pairs
      const u32x4 hv = *(const u32x4*)&hq[qpos(q) * 4];
#pragma unroll
      for (int jj = 0; jj < 4; ++jj) {
        const int p = i4 * 4 + jj;                   // weight pair index
        acc0 = dot2(whh[0][p], hv[jj], acc0);
        acc1 = dot2(whh[1][p], hv[jj], acc1);
        acc2 = dot2(whh[2][p], hv[jj], acc2);
        acc3 = dot2(whh[3][p], hv[jj], acc3);
      }
    }
    acc0 = fmaf(wih[0][0], x0, acc0); acc0 = fmaf(wih[0][1], x1, acc0);
    acc1 = fmaf(wih[1][0], x0, acc1); acc1 = fmaf(wih[1][1], x1, acc1);
    acc2 = fmaf(wih[2][0], x0, acc2); acc2 = fmaf(wih[2][1], x1, acc2);
    acc3 = fmaf(wih[3][0], x0, acc3); acc3 = fmaf(wih[3][1], x1, acc3);

    acc0 = wave_reduce(acc0);
    acc1 = wave_reduce(acc1);
    acc2 = wave_reduce(acc2);
    acc3 = wave_reduce(acc3);

    if (l == 63) {  // own unit: activations + cell update, post to LDS
      const float i_ = fast_sigmoid(acc0 + bias4[0]);
      const float f_ = fast_sigmoid(acc1 + bias4[1]);
      const float g_ = fast_tanh(acc2 + bias4[2]);
      const float o_ = fast_sigmoid(acc3 + bias4[3]);
      cc = fmaf(f_, cc, i_ * g_);
      const float h = o_ * fast_tanh(cc);
      hl = h;
      pub_lds[w] = ((uint32_t)t << 16) | f32_to_f16lo(h);
    }
    // wave 0: gather 8 posted words (LDS spin), ONE coalesced 32B store.
    if (w == 0 && l < UPB) {
      uint32_t v;
      do { v = pub_lds[l]; } while ((v >> 16) != (uint32_t)t);
      st4_sys(&hslots[(size_t)(t & 1) * HID + blk * UPB + l], v);
    }
  }

  // ---- final head: out = h_last . W_lin + b_lin ----
  if (l == 63) red[w] = hl * wlin;
  __syncthreads();
  if (tid == 0) {
    float s = red[0] + red[1] + red[2] + red[3] +
              red[4] + red[5] + red[6] + red[7];
    uint64_t pv = (uint64_t)__float_as_uint(s) |
                  ((uint64_t)(uint32_t)(SEQ + 1) << 32);
    st8_sys(&fbuf[blk], pv);
  }
  if (blk == 0) {
    if (tid < NBLK) {
      uint64_t v;
      do {
        v = ld8_sys(&fbuf[tid]);
      } while ((uint32_t)(v >> 32) != (uint32_t)(SEQ + 1));
      fin[tid] = __uint_as_float((uint32_t)v);
    }
    __syncthreads();
    if (tid == 0) {
      float s = blin[0];
      for (int i = 0; i < NBLK; ++i) s += fin[i];
      out[0] = s;  // deterministic: fixed summation order, no atomics
    }
  }
}

extern "C" void kernel_launch(void* const* d_in, const int* in_sizes, int n_in,
                              void* d_out, int out_size, void* d_ws,
                              size_t ws_size, hipStream_t stream) {
  const float* X    = (const float*)d_in[0];
  const float* Wih  = (const float*)d_in[1];
  const float* Whh  = (const float*)d_in[2];
  const float* bih  = (const float*)d_in[3];
  const float* bhh  = (const float*)d_in[4];
  const float* Wlin = (const float*)d_in[5];
  const float* blin = (const float*)d_in[6];
  float* out   = (float*)d_out;
  uint32_t* ws = (uint32_t*)d_ws;  // uses 18,432 B (hslots + fbuf)

  void* args[] = {(void*)&X,    (void*)&Wih,  (void*)&Whh,
                  (void*)&bih,  (void*)&bhh,  (void*)&Wlin,
                  (void*)&blin, (void*)&out,  (void*)&ws};
  hipLaunchCooperativeKernel((const void*)lstm_persist, dim3(NBLK), dim3(NTHR),
                             args, 0, stream);
}